// Round 12
// baseline (48.739 us; speedup 1.0000x reference)
//
#include <hip/hip_runtime.h>

#define TT   512
#define BB   4
#define OUTL 261632        // per-batch trimmed output length

__device__ __forceinline__ float2 cmul(float2 a, float2 w) {
    return make_float2(a.x * w.x - a.y * w.y, a.x * w.y + a.y * w.x);
}

// radix-4 DIT butterfly (inverse, +i), twiddles w1, w1^2, w1^3 (r3-proven)
__device__ __forceinline__ void bf4(const float2 a[4], float2 o[4], float2 w1) {
    float2 w2 = make_float2(w1.x * w1.x - w1.y * w1.y, 2.f * w1.x * w1.y);
    float2 w3 = cmul(w1, w2);
    float t0r = a[0].x + a[2].x, t0i = a[0].y + a[2].y;
    float t1r = a[0].x - a[2].x, t1i = a[0].y - a[2].y;
    float t2r = a[1].x + a[3].x, t2i = a[1].y + a[3].y;
    float t3r = a[3].y - a[1].y, t3i = a[1].x - a[3].x;   // i*(a1-a3)
    o[0] = make_float2(t0r + t2r, t0i + t2i);
    o[1] = cmul(make_float2(t1r + t3r, t1i + t3i), w1);
    o[2] = cmul(make_float2(t0r - t2r, t0i - t2i), w2);
    o[3] = cmul(make_float2(t1r - t3r, t1i - t3i), w3);
}

// ---- tr_k: X[b][f][t][2] -> Xt[(b*512+t)][f] (float2), 64x64 LDS tiles ----
__global__ __launch_bounds__(256) void tr_k(const float* __restrict__ X,
                                            float* __restrict__ Xt) {
    __shared__ float2 tile[64][65];
    const int f0 = blockIdx.x * 64;
    const int t0 = blockIdx.y * 64;
    const int b  = blockIdx.z;
    const int tid = threadIdx.x;
    #pragma unroll
    for (int it = 0; it < 8; it++) {
        int idx = it * 256 + tid;          // 0..2047
        int fi = idx >> 5;                 // 0..63
        int tj = (idx & 31) * 2;           // 0..62
        const float4 v = *reinterpret_cast<const float4*>(
            X + (((size_t)(b * 2048 + f0 + fi)) * 512 + t0 + tj) * 2);
        tile[fi][tj]     = make_float2(v.x, v.y);
        tile[fi][tj + 1] = make_float2(v.z, v.w);
    }
    __syncthreads();
    #pragma unroll
    for (int it = 0; it < 8; it++) {
        int idx = it * 256 + tid;
        int ti = idx >> 5;
        int fj = (idx & 31) * 2;
        int c  = b * 512 + t0 + ti;
        float2 p = tile[fj][ti];
        float2 q = tile[fj + 1][ti];
        *reinterpret_cast<float4*>(Xt + ((size_t)c * 2048 + f0 + fj) * 2) =
            make_float4(p.x, p.y, q.x, q.y);
    }
}

// ---- fused iSTFT, wave-autonomous FFT: one block = 4 columns, one column
//      per 64-lane wave. 1024-pt packed real-output inverse FFT entirely in
//      registers + shuffles (no barriers, no LDS round trips); one barrier;
//      then r8-style OLA (interior plain stores, seam atomics). ----
__global__ __launch_bounds__(256) void istft_k(const float* __restrict__ Xt,
                                               const float* __restrict__ kc,
                                               const float* __restrict__ ks,
                                               const float* __restrict__ win,
                                               float* __restrict__ out) {
    __shared__ float2 colbuf[4][1024];     // 32 KB, raw z per column

    const int S  = blockIdx.x;             // 0..511
    const int L  = ((S & 7) << 6) | (S >> 3);   // XCD-contiguous remap
    const int c0 = L * 4;
    const int b  = c0 >> 9;
    const int t0 = c0 & 511;               // multiple of 4
    const int tid  = threadIdx.x;
    const int w    = tid >> 6;             // wave -> column
    const int lane = tid & 63;
    const float* twc = kc + 2048;          // cos(2*pi*m/2048) (kernel row n=1)
    const float* tws = ks + 2048;          // +sin (inverse)

    const float2* Xc = reinterpret_cast<const float2*>(Xt) + (size_t)(c0 + w) * 2048;

    // ---- conjugate-pack (r10-proven): Z[k], k = lane + 64a, coalesced ----
    float2 z[16];
    #pragma unroll
    for (int a = 0; a < 16; a++) {
        int k = lane + 64 * a;
        float2 Xk  = Xc[k];
        float2 Xr  = Xc[(2048 - k) & 2047];
        float2 Xk1 = Xc[1024 + k];
        float2 Xm1 = Xc[1024 - k];
        float2 Yk  = make_float2(0.5f * (Xk.x + Xr.x),   0.5f * (Xk.y - Xr.y));
        float2 Yk1 = make_float2(0.5f * (Xk1.x + Xm1.x), 0.5f * (Xk1.y - Xm1.y));
        float2 A = make_float2(Yk.x + Yk1.x, Yk.y + Yk1.y);
        float2 D = make_float2(Yk.x - Yk1.x, Yk.y - Yk1.y);
        float2 Bv = cmul(D, make_float2(twc[k], tws[k]));   // e^{2pi i k/2048}
        z[a] = make_float2(A.x - Bv.y, A.y + Bv.x);         // Z[k] = A + iB
    }

    // ---- in-lane 16-pt DFT over a (radix-4 Stockham, 2 stages) ----
    float2 w16_1 = make_float2(twc[128], tws[128]);
    float2 w16_2 = cmul(w16_1, w16_1);
    float2 w16_3 = cmul(w16_2, w16_1);
    float2 T[16], Sm[16], o[4], ain[4];
    {
        float2 wu[4] = { make_float2(1.f, 0.f), w16_1, w16_2, w16_3 };
        #pragma unroll
        for (int u = 0; u < 4; u++) {
            ain[0] = z[u]; ain[1] = z[u + 4]; ain[2] = z[u + 8]; ain[3] = z[u + 12];
            bf4(ain, o, wu[u]);
            T[4 * u] = o[0]; T[4 * u + 1] = o[1]; T[4 * u + 2] = o[2]; T[4 * u + 3] = o[3];
        }
    }
    #pragma unroll
    for (int u = 0; u < 4; u++) {
        ain[0] = T[u]; ain[1] = T[u + 4]; ain[2] = T[u + 8]; ain[3] = T[u + 12];
        bf4(ain, o, make_float2(1.f, 0.f));
        Sm[u] = o[0]; Sm[u + 4] = o[1]; Sm[u + 8] = o[2]; Sm[u + 12] = o[3];
    }

    // ---- twiddle S[m] *= W1024^{m*lane} (power chain) ----
    {
        float2 wl = make_float2(twc[2 * lane], tws[2 * lane]);
        float2 p = wl;
        #pragma unroll
        for (int m = 1; m < 16; m++) { Sm[m] = cmul(Sm[m], p); p = cmul(p, wl); }
    }

    // ---- cross-lane 64-pt DIF (+i) via shuffles; lane output bit-reversed ----
    #pragma unroll
    for (int st = 0; st < 6; st++) {
        const int h = 32 >> st;
        int idx = (lane & (h - 1)) * (1024 / h);   // W64^{(l&(h-1))*32/h} in 2048-table
        float2 Wf = make_float2(twc[idx], tws[idx]);
        const bool hi = (lane & h) != 0;
        #pragma unroll
        for (int m = 0; m < 16; m++) {
            float2 p = make_float2(__shfl_xor(Sm[m].x, h), __shfl_xor(Sm[m].y, h));
            float2 sum = make_float2(Sm[m].x + p.x, Sm[m].y + p.y);
            float2 dif = cmul(make_float2(p.x - Sm[m].x, p.y - Sm[m].y), Wf);
            Sm[m] = hi ? dif : sum;
        }
    }

    // ---- scatter raw z[j] (j = m + 16q, q = bitrev6(lane)) to LDS ----
    {
        int q = ((lane & 1) << 5) | ((lane & 2) << 3) | ((lane & 4) << 1) |
                ((lane & 8) >> 1) | ((lane & 16) >> 3) | ((lane & 32) >> 5);
        float2* cb = colbuf[w];
        #pragma unroll
        for (int m = 0; m < 16; m++)
            cb[16 * q + ((m + q) & 15)] = Sm[m];   // bank-rotated slot
    }
    __syncthreads();                                // the ONLY barrier

    // ---- OLA + normalization over untrimmed [t0*512, t0*512+3584) ----
    const bool interior = (t0 >= 3) && (t0 <= 507);
    float invw0 = 0.f, invw1 = 0.f;
    {
        float s0 = 0.f, s1 = 0.f;
        #pragma unroll
        for (int kk = 0; kk < 4; kk++) {
            float w0 = win[tid + 512 * kk];
            float w1 = win[tid + 256 + 512 * kk];
            s0 += w0 * w0; s1 += w1 * w1;
        }
        invw0 = 1.0f / (2048.0f * s0);
        invw1 = 1.0f / (2048.0f * s1);
    }
    float* outb = out + (size_t)b * OUTL;
    #pragma unroll 1
    for (int qi = 0; qi < 14; qi++) {
        int jl = tid + 256 * qi;           // 0..3583
        int tb_l = jl >> 9, rr = jl & 511;
        float sum = 0.f;
        #pragma unroll
        for (int k = 0; k < 4; k++) {
            int m = tb_l - k;
            int n = rr + (k << 9);
            if (m >= 0 && m < 4) {
                int j = n >> 1, qq = j >> 4, mm = j & 15;
                float2 v = colbuf[m][16 * qq + ((mm + qq) & 15)];
                sum += ((n & 1) ? v.y : v.x) * win[n];   // frame[2j]=Re, [2j+1]=Im
            }
        }
        float y;
        if (interior) {
            y = sum * ((qi & 1) ? invw1 : invw0);
        } else {
            int tglob = t0 + tb_l;
            float s = 0.f;
            #pragma unroll
            for (int k = 0; k < 4; k++) {
                int t = tglob - k;
                if (t >= 0 && t < TT) { float ww = win[rr + (k << 9)]; s += ww * ww; }
            }
            y = sum * (1.0f / 2048.0f);
            if (s > 1e-10f) y /= s;
        }
        int jp = t0 * 512 + jl - 1024;
        if (jp >= 0 && jp < OUTL) {
            float* dst = outb + jp;
            if (jl >= 1536 && jl < 2048) *dst = y;   // unique-writer core
            else                         atomicAdd(dst, y);
        }
    }
}

extern "C" void kernel_launch(void* const* d_in, const int* in_sizes, int n_in,
                              void* d_out, int out_size, void* d_ws, size_t ws_size,
                              hipStream_t stream) {
    const float* X  = (const float*)d_in[0];
    const float* kc = (const float*)d_in[1];
    const float* ks = (const float*)d_in[2];
    const float* w  = (const float*)d_in[3];
    float* out = (float*)d_out;
    float* Xt  = (float*)d_ws;                 // 2048*2048 float2 = 33.6 MB

    hipMemsetAsync(out, 0, (size_t)out_size * sizeof(float), stream);
    tr_k<<<dim3(32, 8, 4), dim3(256), 0, stream>>>(X, Xt);
    istft_k<<<dim3(BB * TT / 4), dim3(256), 0, stream>>>(Xt, kc, ks, w, out);
}

// Round 14
// 34.939 us; speedup vs baseline: 1.3950x; 1.3950x over previous
//
#include <hip/hip_runtime.h>

#define TT   512
#define BB   4
#define OUTL 261632        // per-batch trimmed output length
#define OUTTOT (BB*OUTL)

#define RS1 36             // A1 row stride (u32 units)
#define RS2 68             // A2 row stride (u32 units)

typedef __attribute__((ext_vector_type(8))) short short8;
typedef __attribute__((ext_vector_type(4))) float f32x4;

__device__ __forceinline__ unsigned short f2bf(float x) {
    union { float f; unsigned int u; } v; v.f = x;
    unsigned int r = v.u + 0x7fffu + ((v.u >> 16) & 1u);   // RNE
    return (unsigned short)(r >> 16);
}
__device__ __forceinline__ unsigned int pack2(float lo, float hi) {
    return ((unsigned int)f2bf(hi) << 16) | (unsigned int)f2bf(lo);
}
__device__ __forceinline__ short8 ld8(const unsigned int* p) {
    return *reinterpret_cast<const short8*>(p);
}

// ---- prep_k: DFT coefficient matrices (bf16 pairs) to global ----
__global__ __launch_bounds__(256) void prep_k(unsigned int* __restrict__ B1g,
                                              unsigned int* __restrict__ B2g) {
    int tid = blockIdx.x * 256 + threadIdx.x;
    if (tid < 2048) {                      // B1g[n<64][j=f2<32]
        int n = tid >> 5, j = tid & 31, n2b = n & 31;
        float ang = (float)((n2b * j) & 31) * 0.19634954084936207f;   // 2pi/32
        float co = __cosf(ang), si = __sinf(ang);
        B1g[n * 32 + j] = (n < 32) ? pack2(co, -si) : pack2(si, co);
    }
    int t2 = tid - 2048;
    if (t2 >= 0 && t2 < 4096) {            // B2g[n1<64][f1<64]
        int n1 = t2 >> 6, f1 = t2 & 63;
        float ang = (float)((n1 * f1) & 63) * 0.09817477042468103f;   // 2pi/64
        float co = __cosf(ang), si = __sinf(ang);
        B2g[n1 * 64 + f1] = pack2(co, -si);
    }
}

// ---- tr_k2: X[b][f][t][2] fp32 -> Xt[c][f] bf16-pair u32 (c = b*512+t) ----
__global__ __launch_bounds__(256) void tr_k2(const float* __restrict__ X,
                                             unsigned int* __restrict__ Xt) {
    __shared__ float2 tile[64][65];
    const int f0 = blockIdx.x * 64;
    const int t0 = blockIdx.y * 64;
    const int b  = blockIdx.z;
    const int tid = threadIdx.x;
    #pragma unroll
    for (int it = 0; it < 8; it++) {
        int idx = it * 256 + tid;
        int fi = idx >> 5;
        int tj = (idx & 31) * 2;
        const float4 v = *reinterpret_cast<const float4*>(
            X + (((size_t)(b * 2048 + f0 + fi)) * 512 + t0 + tj) * 2);
        tile[fi][tj]     = make_float2(v.x, v.y);
        tile[fi][tj + 1] = make_float2(v.z, v.w);
    }
    __syncthreads();
    #pragma unroll
    for (int it = 0; it < 8; it++) {
        int idx = it * 256 + tid;
        int ti = idx >> 5;
        int fj = (idx & 31) * 2;
        int c  = b * 512 + t0 + ti;
        float2 p = tile[fj][ti];
        float2 q = tile[fj + 1][ti];
        uint2 o;
        o.x = pack2(p.x, p.y);             // (re, im) bf16 pair
        o.y = pack2(q.x, q.y);
        *reinterpret_cast<uint2*>(Xt + (size_t)c * 2048 + f0 + fj) = o;
    }
}

// ---- mfma_k: per wave-column 2048-pt inverse DFT as two MFMA stages.
//      x[n2+32n1] = Re sum_{f1} W64^{n1 f1} W2048^{n2 f1}
//                       sum_{f2} W32^{n2 f2} Xc[f1+64 f2]
//      Writes Ft[c][n] = x[n]*win[n] (bf16). No barriers (wave-private LDS).
__global__ __launch_bounds__(128) void mfma_k(const unsigned int* __restrict__ Xt,
                                              const unsigned int* __restrict__ B1g,
                                              const unsigned int* __restrict__ B2g,
                                              unsigned short* __restrict__ Ft) {
    __shared__ unsigned int A1[2][64 * RS1];   // per-col packed X; reused as frame buf
    __shared__ unsigned int A2[2][32 * RS2];   // per-col H (twiddled stage-1 out)

    const int tid = threadIdx.x;
    const int w   = tid >> 6;
    const int l   = tid & 63;
    const int c   = blockIdx.x * 2 + w;
    const int sI  = l & 15, h = l >> 4;

    // ---- stage X -> A1 (per-wave private; lane = f1-row) ----
    const unsigned int* Xc = Xt + (size_t)c * 2048;
    unsigned int* A1w = &A1[w][0];
    #pragma unroll
    for (int j = 0; j < 32; j++) {
        int j2 = (j + (l >> 3)) & 31;           // stagger: spreads LDS banks
        A1w[l * RS1 + j2] = Xc[l + 64 * j2];    // A1[f1=l][f2=j2] = (re,im)
    }

    // ---- stage 1: G[f1][n] = A1 . B1g^T  (M=64, N=64, K=64) ----
    short8 bf[4][2];
    #pragma unroll
    for (int ni = 0; ni < 4; ni++)
        #pragma unroll
        for (int kk = 0; kk < 2; kk++)
            bf[ni][kk] = ld8(&B1g[(16 * ni + sI) * 32 + 16 * kk + 4 * h]);
    f32x4 acc[4][4] = {};
    #pragma unroll
    for (int mi = 0; mi < 4; mi++) {
        short8 af[2];
        #pragma unroll
        for (int kk = 0; kk < 2; kk++)
            af[kk] = ld8(&A1w[(16 * mi + sI) * RS1 + 16 * kk + 4 * h]);
        #pragma unroll
        for (int ni = 0; ni < 4; ni++)
            #pragma unroll
            for (int kk = 0; kk < 2; kk++)
                acc[mi][ni] = __builtin_amdgcn_mfma_f32_16x16x32_bf16(
                    af[kk], bf[ni][kk], acc[mi][ni], 0, 0, 0);
    }

    // ---- fp32 twiddle H = G * W2048^{n2 f1}; write A2[n2][f1] ----
    unsigned int* A2w = &A2[w][0];
    #pragma unroll
    for (int mi = 0; mi < 4; mi++)
        #pragma unroll
        for (int r = 0; r < 4; r++) {
            int f1 = 16 * mi + 4 * h + r;
            #pragma unroll
            for (int ni = 0; ni < 2; ni++) {
                int n2 = 16 * ni + sI;
                float Gre = acc[mi][ni][r];
                float Gim = acc[mi][ni + 2][r];
                float ang = (float)((n2 * f1) & 2047) * 0.0030679615757712823f; // 2pi/2048
                float co = __cosf(ang), si = __sinf(ang);
                float Hre = Gre * co - Gim * si;
                float Him = Gre * si + Gim * co;
                A2w[n2 * RS2 + f1] = pack2(Hre, Him);
            }
        }

    // ---- stage 2: out[n2][n1] = A2 . B2g^T  (M=32, N=64, K=128), real only ----
    short8 b2[4][4];
    #pragma unroll
    for (int ni = 0; ni < 4; ni++)
        #pragma unroll
        for (int kk = 0; kk < 4; kk++)
            b2[ni][kk] = ld8(&B2g[(16 * ni + sI) * 64 + 16 * kk + 4 * h]);
    f32x4 acc2[2][4] = {};
    #pragma unroll
    for (int mi2 = 0; mi2 < 2; mi2++) {
        short8 a2f[4];
        #pragma unroll
        for (int kk = 0; kk < 4; kk++)
            a2f[kk] = ld8(&A2w[(16 * mi2 + sI) * RS2 + 16 * kk + 4 * h]);
        #pragma unroll
        for (int ni = 0; ni < 4; ni++)
            #pragma unroll
            for (int kk = 0; kk < 4; kk++)
                acc2[mi2][ni] = __builtin_amdgcn_mfma_f32_16x16x32_bf16(
                    a2f[kk], b2[ni][kk], acc2[mi2][ni], 0, 0, 0);
    }

    // ---- window + pack frame (bf16) into A1w as fp[n1<64][n2<32], stride 34 ----
    unsigned short* fp = reinterpret_cast<unsigned short*>(A1w);
    #pragma unroll
    for (int mi2 = 0; mi2 < 2; mi2++)
        #pragma unroll
        for (int ni = 0; ni < 4; ni++)
            #pragma unroll
            for (int r = 0; r < 4; r++) {
                int n2 = 16 * mi2 + 4 * h + r;
                int n1 = 16 * ni + sI;
                int n  = n2 + 32 * n1;
                float wv = 0.5f - 0.5f * __cosf((float)n * 0.0030679615757712823f);
                fp[n1 * 34 + n2] = f2bf(acc2[mi2][ni][r] * wv);
            }

    // ---- write Ft[c][n] bf16, coalesced u32 pairs ----
    unsigned int* Fc = reinterpret_cast<unsigned int*>(Ft) + (size_t)c * 1024;
    const unsigned int* fpu = A1w;
    #pragma unroll
    for (int j = 0; j < 16; j++) {
        int n0 = 128 * j + 2 * l;               // even
        Fc[64 * j + l] = fpu[(n0 >> 5) * 17 + ((n0 & 31) >> 1)];
    }
}

// ---- OLA + normalization + trim. Ft is ALREADY windowed (bug fix: no *w). ----
__global__ __launch_bounds__(256) void ola_k(const unsigned short* __restrict__ Ft,
                                             const float* __restrict__ win,
                                             float* __restrict__ out) {
    int j1 = blockIdx.x * 256 + threadIdx.x;
    if (j1 >= OUTTOT) return;
    int b  = j1 / OUTL;
    int jp = j1 - b * OUTL;
    int j  = jp + 1024;             // untrimmed sample index
    int tbase = j >> 9;
    int r = j & 511;
    float acc = 0.f, ws = 0.f;
    #pragma unroll
    for (int k = 0; k < 4; k++) {
        int t = tbase - k;
        if (t >= 0 && t < TT) {
            int n = r + (k << 9);
            float w = win[n];
            unsigned int u = Ft[(size_t)(b * TT + t) * 2048 + n];
            union { unsigned int u; float f; } cv; cv.u = u << 16;
            acc += cv.f;            // frame already windowed in mfma_k
            ws  += w * w;
        }
    }
    float y = acc * (1.0f / 2048.0f);
    if (ws > 1e-10f) y /= ws;
    out[j1] = y;
}

extern "C" void kernel_launch(void* const* d_in, const int* in_sizes, int n_in,
                              void* d_out, int out_size, void* d_ws, size_t ws_size,
                              hipStream_t stream) {
    const float* X  = (const float*)d_in[0];
    const float* w  = (const float*)d_in[3];
    float* out = (float*)d_out;

    unsigned int*   Xt  = (unsigned int*)d_ws;                  // 16.8 MB
    unsigned short* Ft  = (unsigned short*)(Xt + 2048 * 2048);  // 8.4 MB
    unsigned int*   B1g = (unsigned int*)(Ft + 2048 * 2048);    // 8 KB
    unsigned int*   B2g = B1g + 2048;                           // 16 KB

    prep_k<<<dim3(24), dim3(256), 0, stream>>>(B1g, B2g);
    tr_k2<<<dim3(32, 8, 4), dim3(256), 0, stream>>>(X, Xt);
    mfma_k<<<dim3(1024), dim3(128), 0, stream>>>(Xt, B1g, B2g, Ft);
    ola_k<<<dim3((OUTTOT + 255) / 256), dim3(256), 0, stream>>>(Ft, w, out);
}

// Round 15
// 29.673 us; speedup vs baseline: 1.6425x; 1.1775x over previous
//
#include <hip/hip_runtime.h>

#define TT   512
#define BB   4
#define OUTL 261632        // per-batch trimmed output length

typedef __attribute__((ext_vector_type(8))) short short8;
typedef __attribute__((ext_vector_type(4))) float f32x4;

__device__ __forceinline__ unsigned short f2bf(float x) {
    union { float f; unsigned int u; } v; v.f = x;
    unsigned int r = v.u + 0x7fffu + ((v.u >> 16) & 1u);   // RNE
    return (unsigned short)(r >> 16);
}
__device__ __forceinline__ unsigned int pack2(float lo, float hi) {
    return ((unsigned int)f2bf(hi) << 16) | (unsigned int)f2bf(lo);
}
__device__ __forceinline__ short8 ld8(const unsigned int* p) {
    return *reinterpret_cast<const short8*>(p);
}
__device__ __forceinline__ short8 mk8(unsigned int a, unsigned int b,
                                      unsigned int c, unsigned int d) {
    union { uint4 u; short8 s; } v; v.u = make_uint4(a, b, c, d); return v.s;
}

// Fully fused iSTFT: one block = 4 consecutive t-columns, one column per wave.
// Per column: 2048-pt inverse DFT as 64x32 Cooley-Tukey on the matrix pipe
// (stage1 MFMA -> in-register fp32 twiddle -> stage2 MFMA, r14-verified math),
// window, frames to LDS, then r8-proven OLA (interior stores + seam atomics).
__global__ __launch_bounds__(256) void istft_k(const float* __restrict__ X,
                                               const float* __restrict__ win,
                                               float* __restrict__ out) {
    __shared__ unsigned int B2s[4096];     // 16 KB, resident
    __shared__ unsigned int tile[8192];    // 32 KB: B1 transient -> staged cols -> frames

    const int S  = blockIdx.x;             // 0..511
    const int L  = ((S & 7) << 6) | (S >> 3);   // XCD x owns contiguous tiles
    const int c0 = L * 4;
    const int b  = c0 >> 9;
    const int t0 = c0 & 511;               // multiple of 4
    const int tid = threadIdx.x;
    const int w = tid >> 6, l = tid & 63;
    const int sI = l & 15, h = l >> 4;

    // ---- build B1 (into tile, transient) and B2 (resident) ----
    #pragma unroll
    for (int q = 0; q < 8; q++) {
        int i = q * 256 + tid;             // 2048: B1[n<64][f2<32]
        int n = i >> 5, j = i & 31, n2b = n & 31;
        float ang = (float)((n2b * j) & 31) * 0.19634954084936207f;   // 2pi/32
        float co = __cosf(ang), si = __sinf(ang);
        tile[n * 32 + j] = (n < 32) ? pack2(co, -si) : pack2(si, co);
    }
    #pragma unroll
    for (int q = 0; q < 16; q++) {
        int i = q * 256 + tid;             // 4096: B2[n1<64][f1<64]
        int n1 = i >> 6, f1 = i & 63;
        float ang = (float)((n1 * f1) & 63) * 0.09817477042468103f;   // 2pi/64
        B2s[n1 * 64 + f1] = pack2(__cosf(ang), -__sinf(ang));
    }
    __syncthreads();

    // ---- load B fragments to registers ----
    short8 bf[4][2], b2r[4][4];
    #pragma unroll
    for (int ni = 0; ni < 4; ni++) {
        #pragma unroll
        for (int kk = 0; kk < 2; kk++)
            bf[ni][kk] = ld8(&tile[(16 * ni + sI) * 32 + 16 * kk + 4 * h]);
        #pragma unroll
        for (int kk = 0; kk < 4; kk++)
            b2r[ni][kk] = ld8(&B2s[(16 * ni + sI) * 64 + 16 * kk + 4 * h]);
    }
    __syncthreads();                       // B1 area about to be overwritten

    // ---- stage 4 columns: coalesced float4 line loads, bf16-pack ----
    // tile[f*4 + slot], slot = (c + f) & 3 (bank rotation)
    const float* Xb = X + ((size_t)(b * 2048) * 512 + t0) * 2;
    #pragma unroll
    for (int it = 0; it < 16; it++) {
        int idx = it * 256 + tid;          // 0..4095
        int f = idx >> 1, q = idx & 1;
        float4 v = *reinterpret_cast<const float4*>(Xb + ((size_t)f * 512 + 2 * q) * 2);
        tile[f * 4 + ((2 * q + f) & 3)]     = pack2(v.x, v.y);
        tile[f * 4 + ((2 * q + 1 + f) & 3)] = pack2(v.z, v.w);
    }
    __syncthreads();

    // ---- stage 1: G[f1][n] = A . B1^T (M=64 f1, N=64, K=64 real) ----
    const int slot = (w + sI) & 3;
    f32x4 acc[4][4] = {};
    #pragma unroll
    for (int mi = 0; mi < 4; mi++) {
        int f1 = 16 * mi + sI;
        short8 af[2];
        #pragma unroll
        for (int kk = 0; kk < 2; kk++) {
            int f2b = 16 * kk + 4 * h;
            af[kk] = mk8(tile[(f1 + 64 * (f2b + 0)) * 4 + slot],
                         tile[(f1 + 64 * (f2b + 1)) * 4 + slot],
                         tile[(f1 + 64 * (f2b + 2)) * 4 + slot],
                         tile[(f1 + 64 * (f2b + 3)) * 4 + slot]);
        }
        #pragma unroll
        for (int ni = 0; ni < 4; ni++)
            #pragma unroll
            for (int kk = 0; kk < 2; kk++)
                acc[mi][ni] = __builtin_amdgcn_mfma_f32_16x16x32_bf16(
                    af[kk], bf[ni][kk], acc[mi][ni], 0, 0, 0);
    }
    __syncthreads();                       // all waves done reading tile

    // ---- in-register twiddle (A2 frag == lane's own stage-1 output) + stage 2 ----
    f32x4 acc2[2][4] = {};
    #pragma unroll
    for (int mi2 = 0; mi2 < 2; mi2++) {
        const int n2 = 16 * mi2 + sI;
        #pragma unroll
        for (int kk = 0; kk < 4; kk++) {
            unsigned int u0, u1, u2, u3;
            #pragma unroll
            for (int j = 0; j < 4; j++) {
                int f1 = 16 * kk + 4 * h + j;
                float Gre = acc[kk][mi2][j];
                float Gim = acc[kk][mi2 + 2][j];
                float ang = (float)((n2 * f1) & 2047) * 0.0030679615757712823f; // 2pi/2048
                float co = __cosf(ang), si = __sinf(ang);
                unsigned int pv = pack2(Gre * co - Gim * si, Gre * si + Gim * co);
                if (j == 0) u0 = pv; else if (j == 1) u1 = pv;
                else if (j == 2) u2 = pv; else u3 = pv;
            }
            short8 a2f = mk8(u0, u1, u2, u3);
            #pragma unroll
            for (int ni = 0; ni < 4; ni++)
                acc2[mi2][ni] = __builtin_amdgcn_mfma_f32_16x16x32_bf16(
                    a2f, b2r[ni][kk], acc2[mi2][ni], 0, 0, 0);
        }
    }

    // ---- window + pack frames: frames[w][1024] u32 over tile[0..4096) ----
    unsigned int* fw = tile + w * 1024;
    #pragma unroll
    for (int mi2 = 0; mi2 < 2; mi2++)
        #pragma unroll
        for (int ni = 0; ni < 4; ni++) {
            int n1 = 16 * ni + sI;
            #pragma unroll
            for (int rp = 0; rp < 2; rp++) {
                int n2a = 16 * mi2 + 4 * h + 2 * rp;
                int na  = n2a + 32 * n1;
                float w0 = 0.5f - 0.5f * __cosf((float)na * 0.0030679615757712823f);
                float w1 = 0.5f - 0.5f * __cosf((float)(na + 1) * 0.0030679615757712823f);
                fw[(n2a >> 1) + 16 * n1] =
                    pack2(acc2[mi2][ni][2 * rp] * w0, acc2[mi2][ni][2 * rp + 1] * w1);
            }
        }
    __syncthreads();

    // ---- OLA over untrimmed [t0*512, t0*512+3584) ----
    const bool interior = (t0 >= 3) && (t0 <= 505);
    float invw0 = 0.f, invw1 = 0.f;
    {
        float s0 = 0.f, s1 = 0.f;
        #pragma unroll
        for (int k = 0; k < 4; k++) {
            float a = win[tid + 512 * k];
            float c = win[tid + 256 + 512 * k];
            s0 += a * a; s1 += c * c;
        }
        invw0 = 1.0f / (2048.0f * s0);
        invw1 = 1.0f / (2048.0f * s1);
    }
    float* outb = out + (size_t)b * OUTL;
    #pragma unroll 1
    for (int qi = 0; qi < 14; qi++) {
        int jl = tid + 256 * qi;           // 0..3583
        int tb_l = jl >> 9, rr = jl & 511;
        float sum = 0.f;
        #pragma unroll
        for (int k = 0; k < 4; k++) {
            int m = tb_l - k;
            if (m >= 0 && m < 4) {
                int n = rr + (k << 9);
                unsigned int v = tile[m * 1024 + (n >> 1)];
                union { unsigned int u; float f; } cv;
                cv.u = ((n & 1) ? (v >> 16) : (v & 0xffffu)) << 16;
                sum += cv.f;
            }
        }
        int j  = t0 * 512 + jl;
        int jp = j - 1024;
        if (jp < 0 || jp >= OUTL) continue;
        float y;
        if (interior) {
            y = sum * ((qi & 1) ? invw1 : invw0);
        } else {
            int tb = j >> 9;
            float s = 0.f;
            #pragma unroll
            for (int k = 0; k < 4; k++) {
                int t = tb - k;
                if (t >= 0 && t < TT) { float ww = win[rr + (k << 9)]; s += ww * ww; }
            }
            y = sum * (1.0f / 2048.0f);
            if (s > 1e-10f) y /= s;
        }
        if (jl >= 1536 && jl < 2048) outb[jp] = y;     // unique-writer core
        else                         atomicAdd(outb + jp, y);
    }
}

extern "C" void kernel_launch(void* const* d_in, const int* in_sizes, int n_in,
                              void* d_out, int out_size, void* d_ws, size_t ws_size,
                              hipStream_t stream) {
    const float* X  = (const float*)d_in[0];
    const float* w  = (const float*)d_in[3];
    float* out = (float*)d_out;

    hipMemsetAsync(out, 0, (size_t)out_size * sizeof(float), stream);
    istft_k<<<dim3(BB * TT / 4), dim3(256), 0, stream>>>(X, w, out);
}